// Round 5
// baseline (5228.032 us; speedup 1.0000x reference)
//
#include <hip/hip_runtime.h>
#include <hip/hip_bf16.h>

#define NB 128
#define LSEQ 512
#define HD 512
#define MT 128
#define MAX_DEPTH 40

typedef __attribute__((ext_vector_type(8))) short bf16x8;
typedef __attribute__((ext_vector_type(4))) float f32x4;

static __device__ __forceinline__ unsigned short f2b(float x) {
    union { __hip_bfloat16 b; unsigned short u; } cv;
    cv.b = __float2bfloat16(x);
    return cv.u;
}
static __device__ __forceinline__ float b2f(unsigned short u) {
    union { __hip_bfloat16 b; unsigned short u; } cv;
    cv.u = u;
    return __bfloat162float(cv.b);
}

// ---------------------------------------------------------------------------
// setup: combined biases, h0 -> bf16, zero page
// ---------------------------------------------------------------------------
__global__ __launch_bounds__(256) void setup_kernel(
    const float* __restrict__ b_ih, const float* __restrict__ b_hh,
    const float* __restrict__ h0,
    float* __restrict__ bias4, unsigned short* __restrict__ h0bf,
    unsigned short* __restrict__ zeropage)
{
    int i = blockIdx.x * 256 + threadIdx.x;
    if (i < NB * HD) h0bf[i] = f2b(h0[i]);
    if (i < HD) {
        bias4[i]        = b_ih[i]        + b_hh[i];         // r
        bias4[512 + i]  = b_ih[512 + i]  + b_hh[512 + i];   // z
        bias4[1024 + i] = b_ih[1024 + i];                   // n (x side)
        bias4[1536 + i] = b_hh[1024 + i];                   // n (h side)
    }
    if (i < 2048) zeropage[i] = 0;
}

// ---------------------------------------------------------------------------
// pack: W_ih/W_hh [1536][512] row-major -> MFMA-B-frag-major bf16.
// lane l of frag (ct,kc) holds B[k=kc*32+(l>>4)*8+j][col=ct*16+(l&15)], j=0..7
// element index: ((ct*16+kc)*64 + lane)*8 + j
// ---------------------------------------------------------------------------
__global__ __launch_bounds__(256) void pack_kernel(
    const float* __restrict__ W_ih, const float* __restrict__ W_hh,
    unsigned short* __restrict__ Xpack, unsigned short* __restrict__ Hpack)
{
    int idx = blockIdx.x * 256 + threadIdx.x;   // = g*512 + k
    if (idx >= 1536 * 512) return;
    int g = idx >> 9, k = idx & 511;
    int ct = g >> 4, lane_lo = g & 15;
    int kc = k >> 5, kin = k & 31;
    int lane = (kin >> 3) * 16 + lane_lo;
    int j = kin & 7;
    int p = ((ct * 16 + kc) * 64 + lane) * 8 + j;
    Xpack[p] = f2b(W_ih[idx]);
    Hpack[p] = f2b(W_hh[idx]);
}

// ---------------------------------------------------------------------------
// xcvt: input fp32 -> bf16 (once)
// ---------------------------------------------------------------------------
__global__ __launch_bounds__(256) void xcvt_kernel(
    const float* __restrict__ inp, unsigned short* __restrict__ xbf)
{
    size_t i = ((size_t)blockIdx.x * 256 + threadIdx.x) * 8;
    float4 v0 = *(const float4*)(inp + i);
    float4 v1 = *(const float4*)(inp + i + 4);
    uint4 u;
    u.x = (unsigned)f2b(v0.x) | ((unsigned)f2b(v0.y) << 16);
    u.y = (unsigned)f2b(v0.z) | ((unsigned)f2b(v0.w) << 16);
    u.z = (unsigned)f2b(v1.x) | ((unsigned)f2b(v1.y) << 16);
    u.w = (unsigned)f2b(v1.z) | ((unsigned)f2b(v1.w) << 16);
    *(uint4*)(xbf + i) = u;
}

// ---------------------------------------------------------------------------
// sched: bucket (n,l) items by depth-within-episode
// ---------------------------------------------------------------------------
__global__ __launch_bounds__(128) void sched_kernel(
    const int* __restrict__ is_init,
    int* __restrict__ counts_g, int* __restrict__ offsets_g,
    unsigned* __restrict__ items_g)
{
    __shared__ int cnt[LSEQ];
    __shared__ int off[LSEQ];
    int tid = threadIdx.x;
    for (int i = tid; i < LSEQ; i += 128) cnt[i] = 0;
    __syncthreads();
    {
        int d = 0;
        for (int l = 0; l < LSEQ; l++) {
            int ii = is_init[tid * LSEQ + l];
            d = ii ? 0 : (l == 0 ? 0 : d + 1);
            atomicAdd(&cnt[d], 1);
        }
    }
    __syncthreads();
    if (tid == 0) {
        int acc = 0;
        for (int i = 0; i < LSEQ; i++) { off[i] = acc; acc += cnt[i]; }
    }
    __syncthreads();
    for (int i = tid; i < LSEQ; i += 128) {
        counts_g[i] = cnt[i];
        offsets_g[i] = off[i];
        cnt[i] = 0;
    }
    __syncthreads();
    {
        int d = 0;
        for (int l = 0; l < LSEQ; l++) {
            int ii = is_init[tid * LSEQ + l];
            d = ii ? 0 : (l == 0 ? 0 : d + 1);
            int pos = off[d] + atomicAdd(&cnt[d], 1);
            items_g[pos] = (unsigned)((tid << 16) | l);
        }
    }
}

// ---------------------------------------------------------------------------
// phase: depth-d GRU step. Block = 128 items x 128 cols-per-gate (blockIdx.y
// = col slice 0..3). 8 waves = 2 item-groups x 4 col-groups; per wave 64
// items x 32 cols of each gate -> acc 32 x f32x4. K chunked 4x128 per half
// (X then H), bf16 LDS tile with XOR swizzle folded into the SOURCE address,
// register-staged (issue-early / write-late).
// ---------------------------------------------------------------------------
__global__ __launch_bounds__(512, 2) void phase_kernel(
    int d,
    const unsigned short* __restrict__ Xpack, const unsigned short* __restrict__ Hpack,
    const float* __restrict__ bias4,
    const int* __restrict__ counts, const int* __restrict__ offsets,
    const unsigned* __restrict__ items,
    const unsigned short* __restrict__ xbf, const unsigned short* __restrict__ h0bf,
    const unsigned short* __restrict__ zeropage,
    const int* __restrict__ is_init,
    unsigned short* __restrict__ hbf)
{
    const int count = counts[d];
    if (count == 0) return;
    const int base = offsets[d];
    const int tid = threadIdx.x;
    const int w = tid >> 6, lane = tid & 63;
    const int l15 = lane & 15, lhi = lane >> 4;
    const int mg = w >> 2, cg = w & 3;
    const int cs = blockIdx.y;

    __shared__ unsigned short As[MT * 128];    // 32 KB staged K-chunk
    __shared__ const unsigned short* px[MT];
    __shared__ const unsigned short* ph[MT];
    __shared__ unsigned short* pout[MT];

    // per-wave bias registers (cols fixed)
    float br[2], bz[2], bnx[2], bnh[2];
    #pragma unroll
    for (int cf = 0; cf < 2; ++cf) {
        int col = cs * 128 + cg * 32 + cf * 16 + l15;
        br[cf]  = bias4[col];
        bz[cf]  = bias4[512 + col];
        bnx[cf] = bias4[1024 + col];
        bnh[cf] = bias4[1536 + col];
    }
    const int ctg = cs * 8 + cg * 2;
    const unsigned short* xpk = Xpack + lane * 8;
    const unsigned short* hpk = Hpack + lane * 8;

    const int ntiles = (count + MT - 1) >> 7;
    for (int tile = blockIdx.x; tile < ntiles; tile += gridDim.x) {
        __syncthreads();   // prior tile's epilogue done with ptr arrays
        if (tid < MT) {
            int g = tile * MT + tid;
            if (g < count) {
                unsigned wv = items[base + g];
                int n = (int)(wv >> 16), l = (int)(wv & 0xffff);
                size_t ro = ((size_t)(n * LSEQ + l)) * HD;
                px[tid] = xbf + ro;
                pout[tid] = hbf + ro;
                ph[tid] = (d > 0) ? (hbf + ro - HD)
                          : (is_init[n * LSEQ + l] ? zeropage : h0bf + (size_t)n * HD);
            } else {
                px[tid] = zeropage; ph[tid] = zeropage; pout[tid] = nullptr;
            }
        }
        __syncthreads();

        f32x4 accR[4][2], accZ[4][2], accNX[4][2], accNH[4][2];
        #pragma unroll
        for (int mf = 0; mf < 4; ++mf)
        #pragma unroll
        for (int cf = 0; cf < 2; ++cf) {
            accR[mf][cf]  = (f32x4){br[cf], br[cf], br[cf], br[cf]};
            accZ[mf][cf]  = (f32x4){bz[cf], bz[cf], bz[cf], bz[cf]};
            accNX[mf][cf] = (f32x4){bnx[cf], bnx[cf], bnx[cf], bnx[cf]};
            accNH[mf][cf] = (f32x4){bnh[cf], bnh[cf], bnh[cf], bnh[cf]};
        }

        // prologue: chunk 0 (X half, k-chunk 0) into regs
        uint4 st[4];
        #pragma unroll
        for (int i = 0; i < 4; ++i) {
            int c = i * 512 + tid;
            int row = c >> 4, slot = c & 15;
            st[i] = *(const uint4*)(px[row] + ((slot ^ (row & 7)) << 3));
        }

        #pragma unroll
        for (int p = 0; p < 8; ++p) {
            __syncthreads();   // all waves done reading As (chunk p-1)
            #pragma unroll
            for (int i = 0; i < 4; ++i) {
                int c = i * 512 + tid;
                *(uint4*)((char*)As + c * 16) = st[i];
            }
            __syncthreads();   // chunk p visible
            if (p < 7) {       // issue-early: next chunk loads hide under MFMA
                const int kch = (p + 1) & 3;
                #pragma unroll
                for (int i = 0; i < 4; ++i) {
                    int c = i * 512 + tid;
                    int row = c >> 4, slot = c & 15;
                    const unsigned short* bp = ((p + 1) >= 4) ? ph[row] : px[row];
                    st[i] = *(const uint4*)(bp + kch * 128 + ((slot ^ (row & 7)) << 3));
                }
            }
            const unsigned short* pk = (p < 4) ? xpk : hpk;
            #pragma unroll
            for (int kcl = 0; kcl < 4; ++kcl) {
                const int kcg = (p & 3) * 4 + kcl;
                bf16x8 a[4];
                #pragma unroll
                for (int mf = 0; mf < 4; ++mf) {
                    int row = mg * 64 + mf * 16 + l15;
                    int byte = row * 256 + ((((kcl * 32 + lhi * 8)) << 1) ^ ((row & 7) << 4));
                    a[mf] = *(const bf16x8*)((const char*)As + byte);
                }
                #pragma unroll
                for (int cf = 0; cf < 2; ++cf) {
                    const int ct = ctg + cf;
                    bf16x8 bR = *(const bf16x8*)(pk + (size_t)((ct)*16 + kcg) * 512);
                    bf16x8 bZ = *(const bf16x8*)(pk + (size_t)((32 + ct) * 16 + kcg) * 512);
                    bf16x8 bN = *(const bf16x8*)(pk + (size_t)((64 + ct) * 16 + kcg) * 512);
                    #pragma unroll
                    for (int mf = 0; mf < 4; ++mf) {
                        accR[mf][cf] = __builtin_amdgcn_mfma_f32_16x16x32_bf16(a[mf], bR, accR[mf][cf], 0, 0, 0);
                        accZ[mf][cf] = __builtin_amdgcn_mfma_f32_16x16x32_bf16(a[mf], bZ, accZ[mf][cf], 0, 0, 0);
                        if (p < 4)
                            accNX[mf][cf] = __builtin_amdgcn_mfma_f32_16x16x32_bf16(a[mf], bN, accNX[mf][cf], 0, 0, 0);
                        else
                            accNH[mf][cf] = __builtin_amdgcn_mfma_f32_16x16x32_bf16(a[mf], bN, accNH[mf][cf], 0, 0, 0);
                    }
                }
            }
        }

        // epilogue: GRU pointwise (C/D: item=(lane>>4)*4+v, col=lane&15)
        #pragma unroll
        for (int mf = 0; mf < 4; ++mf)
        #pragma unroll
        for (int v = 0; v < 4; ++v) {
            int row = mg * 64 + mf * 16 + lhi * 4 + v;
            unsigned short* po = pout[row];
            if (po == nullptr) continue;
            const unsigned short* hp = ph[row];
            #pragma unroll
            for (int cf = 0; cf < 2; ++cf) {
                int col = cs * 128 + cg * 32 + cf * 16 + l15;
                float hprev = b2f(hp[col]);
                float r = 1.f / (1.f + __expf(-accR[mf][cf][v]));
                float z = 1.f / (1.f + __expf(-accZ[mf][cf][v]));
                float nn = tanhf(accNX[mf][cf][v] + r * accNH[mf][cf][v]);
                po[col] = f2b((1.f - z) * nn + z * hprev);
            }
        }
    }
}

// ---------------------------------------------------------------------------
// hlast: copy h[n, L-1, :] (bf16) -> fp32 scratch (before hexp overwrites)
// ---------------------------------------------------------------------------
__global__ __launch_bounds__(256) void hlast_kernel(
    const unsigned short* __restrict__ hbf, float* __restrict__ hlast)
{
    int i = blockIdx.x * 256 + threadIdx.x;
    if (i >= NB * HD) return;
    int n = i >> 9, c = i & 511;
    hlast[i] = b2f(hbf[((size_t)(n * LSEQ + (LSEQ - 1))) * HD + c]);
}

// ---------------------------------------------------------------------------
// LayerNorm: out1 = LN(hbf + inp) * gamma + beta   (reads bf16 h)
// ---------------------------------------------------------------------------
__global__ __launch_bounds__(256) void ln_kernel(
    const unsigned short* __restrict__ hbf, const float* __restrict__ inp,
    const float* __restrict__ gamma, const float* __restrict__ beta,
    float* __restrict__ out1)
{
    size_t row = blockIdx.x;
    int tid = threadIdx.x;
    const unsigned short* yrow = hbf + row * HD;
    const float* xrow = inp + row * HD;
    float a = b2f(yrow[tid]) + xrow[tid];
    float b = b2f(yrow[tid + 256]) + xrow[tid + 256];
    float s = a + b, ss = a * a + b * b;
    #pragma unroll
    for (int m = 1; m < 64; m <<= 1) {
        s  += __shfl_xor(s, m, 64);
        ss += __shfl_xor(ss, m, 64);
    }
    __shared__ float ps[4], pss[4];
    int w = tid >> 6;
    if ((tid & 63) == 0) { ps[w] = s; pss[w] = ss; }
    __syncthreads();
    s  = ps[0] + ps[1] + ps[2] + ps[3];
    ss = pss[0] + pss[1] + pss[2] + pss[3];
    float mu = s * (1.f / 512.f);
    float var = ss * (1.f / 512.f) - mu * mu;
    float inv = rsqrtf(var + 1e-5f);
    float* orow = out1 + row * HD;
    orow[tid]       = (a - mu) * inv * gamma[tid] + beta[tid];
    orow[tid + 256] = (b - mu) * inv * gamma[tid + 256] + beta[tid + 256];
}

// ---------------------------------------------------------------------------
// hexp: out2[n,l,:] = hlast[n,:]  (overwrites the xbf/hbf scratch; runs last)
// ---------------------------------------------------------------------------
__global__ __launch_bounds__(256) void hexp_kernel(
    const float* __restrict__ hlast, float* __restrict__ out2)
{
    size_t idx = (size_t)blockIdx.x * 256 + threadIdx.x;   // float4 units
    if (idx >= (size_t)NB * LSEQ * HD / 4) return;
    int per_n = LSEQ * HD / 4;
    int n = (int)(idx / per_n);
    int c4 = (int)(idx & (HD / 4 - 1));
    float4 v = *(const float4*)(hlast + n * HD + c4 * 4);
    *(float4*)(out2 + idx * 4) = v;
}

// ---------------------------------------------------------------------------
extern "C" void kernel_launch(void* const* d_in, const int* in_sizes, int n_in,
                              void* d_out, int out_size, void* d_ws, size_t ws_size,
                              hipStream_t stream)
{
    const float* inp   = (const float*)d_in[0];
    const float* h0    = (const float*)d_in[1];
    const int*  is_ini = (const int*)d_in[2];
    const float* W_ih  = (const float*)d_in[3];
    const float* W_hh  = (const float*)d_in[4];
    const float* b_ih  = (const float*)d_in[5];
    const float* b_hh  = (const float*)d_in[6];
    const float* gamma = (const float*)d_in[7];
    const float* beta  = (const float*)d_in[8];

    const size_t NLH = (size_t)NB * LSEQ * HD;   // 33,554,432
    float* out1 = (float*)d_out;
    float* out2 = out1 + NLH;
    // out2 region doubles as bf16 scratch: xbf (67MB) + hbf (67MB) = exactly 134MB
    unsigned short* xbf = (unsigned short*)out2;
    unsigned short* hbf = xbf + NLH;

    unsigned short* Xpack = (unsigned short*)d_ws;           // 1.5 MB
    unsigned short* Hpack = Xpack + 1536 * 512;              // 1.5 MB
    float* bias4 = (float*)(Hpack + 1536 * 512);             // 8 KB
    int* counts  = (int*)(bias4 + 2048);
    int* offsets = counts + LSEQ;
    unsigned* items = (unsigned*)(offsets + LSEQ);           // 256 KB
    unsigned short* h0bf = (unsigned short*)(items + NB * LSEQ);  // 128 KB
    unsigned short* zeropage = h0bf + NB * HD;               // 4 KB
    float* hlast = (float*)(zeropage + 2048);                // 256 KB

    setup_kernel<<<(NB * HD + 255) / 256, 256, 0, stream>>>(
        b_ih, b_hh, h0, bias4, h0bf, zeropage);
    pack_kernel<<<(1536 * 512 + 255) / 256, 256, 0, stream>>>(W_ih, W_hh, Xpack, Hpack);
    xcvt_kernel<<<(int)(NLH / 8 / 256), 256, 0, stream>>>(inp, xbf);
    sched_kernel<<<1, 128, 0, stream>>>(is_ini, counts, offsets, items);

    for (int d = 0; d < MAX_DEPTH; d++) {
        int gx = 256 >> d;
        if (gx < 4) gx = 4;
        phase_kernel<<<dim3(gx, 4), 512, 0, stream>>>(
            d, Xpack, Hpack, bias4, counts, offsets, items,
            xbf, h0bf, zeropage, is_ini, hbf);
    }

    hlast_kernel<<<(NB * HD + 255) / 256, 256, 0, stream>>>(hbf, hlast);
    ln_kernel<<<NB * LSEQ, 256, 0, stream>>>(hbf, inp, gamma, beta, out1);
    hexp_kernel<<<(int)(NLH / 4 / 256), 256, 0, stream>>>(hlast, out2);
}

// Round 6
// 2522.421 us; speedup vs baseline: 2.0726x; 2.0726x over previous
//
#include <hip/hip_runtime.h>
#include <hip/hip_bf16.h>

#define NB 128
#define LSEQ 512
#define HD 512
#define NI (NB * LSEQ)
#define MAX_DEPTH 40

typedef __attribute__((ext_vector_type(8))) short bf16x8;
typedef __attribute__((ext_vector_type(4))) float f32x4;

static __device__ __forceinline__ unsigned f2b(float x) {
    union { __hip_bfloat16 b; unsigned short u; } cv;
    cv.b = __float2bfloat16(x);
    return (unsigned)cv.u;
}
static __device__ __forceinline__ float b2f(unsigned short u) {
    union { __hip_bfloat16 b; unsigned short u; } cv;
    cv.u = u;
    return __bfloat162float(cv.b);
}

// ---------------------------------------------------------------------------
// setup: h0 -> bf16, zero page
// ---------------------------------------------------------------------------
__global__ __launch_bounds__(256) void setup_kernel(
    const float* __restrict__ h0,
    unsigned short* __restrict__ h0bf, unsigned short* __restrict__ zeropage)
{
    int i = blockIdx.x * 256 + threadIdx.x;
    if (i < NB * HD) h0bf[i] = (unsigned short)f2b(h0[i]);
    if (i < 1024) zeropage[i] = 0;
}

// ---------------------------------------------------------------------------
// pack: W [1536][512] row-major -> MFMA-B-frag-major bf16.
// lane l of frag (ct,kc) holds B[k=kc*32+(l>>4)*8+j][col=ct*16+(l&15)], j=0..7
// element index: ((ct*16+kc)*64 + lane)*8 + j
// ---------------------------------------------------------------------------
__global__ __launch_bounds__(256) void pack_kernel(
    const float* __restrict__ W_ih, const float* __restrict__ W_hh,
    unsigned short* __restrict__ Xpack, unsigned short* __restrict__ Hpack)
{
    int idx = blockIdx.x * 256 + threadIdx.x;   // = g*512 + k
    if (idx >= 1536 * 512) return;
    int g = idx >> 9, k = idx & 511;
    int ct = g >> 4, lane_lo = g & 15;
    int kc = k >> 5, kin = k & 31;
    int lane = (kin >> 3) * 16 + lane_lo;
    int j = kin & 7;
    int p = ((ct * 16 + kc) * 64 + lane) * 8 + j;
    Xpack[p] = (unsigned short)f2b(W_ih[idx]);
    Hpack[p] = (unsigned short)f2b(W_hh[idx]);
}

// ---------------------------------------------------------------------------
// sched: bucket (n,l) items by depth-within-episode
// ---------------------------------------------------------------------------
__global__ __launch_bounds__(128) void sched_kernel(
    const int* __restrict__ is_init,
    int* __restrict__ counts_g, int* __restrict__ offsets_g,
    unsigned* __restrict__ items_g)
{
    __shared__ int cnt[LSEQ];
    __shared__ int off[LSEQ];
    int tid = threadIdx.x;
    for (int i = tid; i < LSEQ; i += 128) cnt[i] = 0;
    __syncthreads();
    {
        int d = 0;
        for (int l = 0; l < LSEQ; l++) {
            int ii = is_init[tid * LSEQ + l];
            d = ii ? 0 : (l == 0 ? 0 : d + 1);
            atomicAdd(&cnt[d], 1);
        }
    }
    __syncthreads();
    if (tid == 0) {
        int acc = 0;
        for (int i = 0; i < LSEQ; i++) { off[i] = acc; acc += cnt[i]; }
    }
    __syncthreads();
    for (int i = tid; i < LSEQ; i += 128) {
        counts_g[i] = cnt[i];
        offsets_g[i] = off[i];
        cnt[i] = 0;
    }
    __syncthreads();
    {
        int d = 0;
        for (int l = 0; l < LSEQ; l++) {
            int ii = is_init[tid * LSEQ + l];
            d = ii ? 0 : (l == 0 ? 0 : d + 1);
            int pos = off[d] + atomicAdd(&cnt[d], 1);
            items_g[pos] = (unsigned)((tid << 16) | l);
        }
    }
}

// ---------------------------------------------------------------------------
// gx: dense GEMM gx_g = x @ W_ih_g^T + b_ih_g for all 65536 items, one gate
// per blockIdx.y. Block = 64 items x 512 cols (of that gate), 8 waves: wave w
// owns cols [64w, 64w+64). acc 16 x f32x4. K chunked 2x256 via 32KB LDS.
// ---------------------------------------------------------------------------
__global__ __launch_bounds__(512, 2) void gx_kernel(
    const float* __restrict__ inp, const unsigned short* __restrict__ Xpack,
    const float* __restrict__ b_ih,
    unsigned short* __restrict__ gxr, unsigned short* __restrict__ gxz,
    unsigned short* __restrict__ gxn)
{
    const int g = blockIdx.y;                 // gate 0,1,2
    const int row0 = blockIdx.x * 64;         // 1024 item-tiles
    const int tid = threadIdx.x;
    const int w = tid >> 6, lane = tid & 63;
    const int l15 = lane & 15, lhi = lane >> 4;

    __shared__ unsigned short As[64 * 256];   // 32 KB bf16, XOR-swizzled

    unsigned short* gout = (g == 0) ? gxr : (g == 1) ? gxz : gxn;

    f32x4 acc[4][4];
    #pragma unroll
    for (int cf = 0; cf < 4; ++cf) {
        float b = b_ih[g * 512 + w * 64 + cf * 16 + l15];
        #pragma unroll
        for (int mf = 0; mf < 4; ++mf) acc[mf][cf] = (f32x4){b, b, b, b};
    }
    const unsigned short* xpk = Xpack + lane * 8;

    #pragma unroll
    for (int ch = 0; ch < 2; ++ch) {
        __syncthreads();
        {
            int r = tid >> 3, kb = (tid & 7) * 32;
            const float* src = inp + (size_t)(row0 + r) * 512 + ch * 256 + kb;
            #pragma unroll
            for (int i = 0; i < 4; ++i) {
                float4 v0 = *(const float4*)(src + i * 8);
                float4 v1 = *(const float4*)(src + i * 8 + 4);
                uint4 u;
                u.x = f2b(v0.x) | (f2b(v0.y) << 16);
                u.y = f2b(v0.z) | (f2b(v0.w) << 16);
                u.z = f2b(v1.x) | (f2b(v1.y) << 16);
                u.w = f2b(v1.z) | (f2b(v1.w) << 16);
                int byte = (r * 512 + (kb + i * 8) * 2) ^ ((r & 7) << 4);
                *(uint4*)((char*)As + byte) = u;
            }
        }
        __syncthreads();
        #pragma unroll
        for (int kcl = 0; kcl < 8; ++kcl) {
            const int kcg = ch * 8 + kcl;
            bf16x8 a[4];
            #pragma unroll
            for (int mf = 0; mf < 4; ++mf) {
                int r = mf * 16 + l15;
                int byte = (r * 512 + (kcl * 32 + lhi * 8) * 2) ^ ((r & 7) << 4);
                a[mf] = *(const bf16x8*)((const char*)As + byte);
            }
            #pragma unroll
            for (int cf = 0; cf < 4; ++cf) {
                int ct = g * 32 + w * 4 + cf;
                bf16x8 bv = *(const bf16x8*)(xpk + (size_t)(ct * 16 + kcg) * 512);
                #pragma unroll
                for (int mf = 0; mf < 4; ++mf)
                    acc[mf][cf] = __builtin_amdgcn_mfma_f32_16x16x32_bf16(a[mf], bv, acc[mf][cf], 0, 0, 0);
            }
        }
    }

    #pragma unroll
    for (int mf = 0; mf < 4; ++mf)
    #pragma unroll
    for (int v = 0; v < 4; ++v) {
        size_t it = (size_t)(row0 + mf * 16 + lhi * 4 + v);
        #pragma unroll
        for (int cf = 0; cf < 4; ++cf) {
            int col = w * 64 + cf * 16 + l15;
            gout[it * 512 + col] = (unsigned short)f2b(acc[mf][cf][v]);
        }
    }
}

// ---------------------------------------------------------------------------
// phase: H-side GEMM + fused GRU epilogue for all items at depth d.
// Block = 64 items x 256 cols/gate (blockIdx.y = col half). 8 waves: wave w
// owns cols [32w, 32w+32) of each gate -> acc 24 x f32x4 (96 regs).
// ---------------------------------------------------------------------------
__global__ __launch_bounds__(512, 2) void phase_kernel(
    int d,
    const unsigned short* __restrict__ Hpack, const float* __restrict__ b_hh,
    const int* __restrict__ counts, const int* __restrict__ offsets,
    const unsigned* __restrict__ items,
    const unsigned short* __restrict__ gxr, const unsigned short* __restrict__ gxz,
    const unsigned short* __restrict__ gxn,
    const unsigned short* __restrict__ h0bf, const unsigned short* __restrict__ zeropage,
    const int* __restrict__ is_init,
    unsigned short* __restrict__ hbf)
{
    const int count = counts[d];
    if (count == 0) return;
    const int base = offsets[d];
    const int y = blockIdx.y;
    const int tid = threadIdx.x;
    const int w = tid >> 6, lane = tid & 63;
    const int l15 = lane & 15, lhi = lane >> 4;

    __shared__ unsigned short As[64 * 256];   // 32 KB

    float bR[2], bZ[2], bN[2];
    #pragma unroll
    for (int cf = 0; cf < 2; ++cf) {
        int colg = y * 256 + w * 32 + cf * 16 + l15;
        bR[cf] = b_hh[colg];
        bZ[cf] = b_hh[512 + colg];
        bN[cf] = b_hh[1024 + colg];
    }
    const unsigned short* hpk = Hpack + lane * 8;

    const int ntiles = (count + 63) >> 6;
    for (int tile = blockIdx.x; tile < ntiles; tile += gridDim.x) {
        f32x4 aR[4][2], aZ[4][2], aN[4][2];
        #pragma unroll
        for (int mf = 0; mf < 4; ++mf)
        #pragma unroll
        for (int cf = 0; cf < 2; ++cf) {
            aR[mf][cf] = (f32x4){bR[cf], bR[cf], bR[cf], bR[cf]};
            aZ[mf][cf] = (f32x4){bZ[cf], bZ[cf], bZ[cf], bZ[cf]};
            aN[mf][cf] = (f32x4){bN[cf], bN[cf], bN[cf], bN[cf]};
        }

        #pragma unroll
        for (int ch = 0; ch < 2; ++ch) {
            __syncthreads();    // prev chunk's readers done
            {
                int r = tid >> 3, kb = (tid & 7) * 32;
                int g = tile * 64 + r;
                uint4 u[4];
                #pragma unroll
                for (int i = 0; i < 4; ++i) u[i] = make_uint4(0, 0, 0, 0);
                if (g < count) {
                    unsigned wv = items[base + g];
                    int n = (int)(wv >> 16), l = (int)(wv & 0xffff);
                    size_t ro = ((size_t)(n * LSEQ + l)) * HD;
                    const unsigned short* src;
                    if (d > 0) src = hbf + ro - HD;
                    else src = is_init[n * LSEQ + l] ? zeropage : h0bf + (size_t)n * HD;
                    src += ch * 256 + kb;
                    #pragma unroll
                    for (int i = 0; i < 4; ++i) u[i] = *(const uint4*)(src + i * 8);
                }
                #pragma unroll
                for (int i = 0; i < 4; ++i) {
                    int byte = (r * 512 + (kb + i * 8) * 2) ^ ((r & 7) << 4);
                    *(uint4*)((char*)As + byte) = u[i];
                }
            }
            __syncthreads();
            #pragma unroll
            for (int kcl = 0; kcl < 8; ++kcl) {
                const int kcg = ch * 8 + kcl;
                bf16x8 a[4];
                #pragma unroll
                for (int mf = 0; mf < 4; ++mf) {
                    int r = mf * 16 + l15;
                    int byte = (r * 512 + (kcl * 32 + lhi * 8) * 2) ^ ((r & 7) << 4);
                    a[mf] = *(const bf16x8*)((const char*)As + byte);
                }
                #pragma unroll
                for (int cf = 0; cf < 2; ++cf) {
                    const int ctb = y * 16 + w * 2 + cf;
                    bf16x8 vR = *(const bf16x8*)(hpk + (size_t)(ctb * 16 + kcg) * 512);
                    bf16x8 vZ = *(const bf16x8*)(hpk + (size_t)((32 + ctb) * 16 + kcg) * 512);
                    bf16x8 vN = *(const bf16x8*)(hpk + (size_t)((64 + ctb) * 16 + kcg) * 512);
                    #pragma unroll
                    for (int mf = 0; mf < 4; ++mf) {
                        aR[mf][cf] = __builtin_amdgcn_mfma_f32_16x16x32_bf16(a[mf], vR, aR[mf][cf], 0, 0, 0);
                        aZ[mf][cf] = __builtin_amdgcn_mfma_f32_16x16x32_bf16(a[mf], vZ, aZ[mf][cf], 0, 0, 0);
                        aN[mf][cf] = __builtin_amdgcn_mfma_f32_16x16x32_bf16(a[mf], vN, aN[mf][cf], 0, 0, 0);
                    }
                }
            }
        }

        // epilogue: GRU pointwise (C/D: item=(lane>>4)*4+v, col=lane&15)
        #pragma unroll
        for (int mf = 0; mf < 4; ++mf)
        #pragma unroll
        for (int v = 0; v < 4; ++v) {
            int g = tile * 64 + mf * 16 + lhi * 4 + v;
            if (g >= count) continue;
            unsigned wv = items[base + g];
            int n = (int)(wv >> 16), l = (int)(wv & 0xffff);
            size_t ro = ((size_t)(n * LSEQ + l)) * HD;
            const unsigned short* hsrc = (d > 0) ? (hbf + ro - HD)
                : (is_init[n * LSEQ + l] ? zeropage : h0bf + (size_t)n * HD);
            #pragma unroll
            for (int cf = 0; cf < 2; ++cf) {
                int colg = y * 256 + w * 32 + cf * 16 + l15;
                float gr = b2f(gxr[ro + colg]);
                float gz = b2f(gxz[ro + colg]);
                float gn = b2f(gxn[ro + colg]);
                float hp = b2f(hsrc[colg]);
                float r = 1.f / (1.f + __expf(-(gr + aR[mf][cf][v])));
                float z = 1.f / (1.f + __expf(-(gz + aZ[mf][cf][v])));
                float nn = tanhf(gn + r * aN[mf][cf][v]);
                hbf[ro + colg] = (unsigned short)f2b((1.f - z) * nn + z * hp);
            }
        }
    }
}

// ---------------------------------------------------------------------------
// hlast: h[n, L-1, :] (bf16) -> fp32 ws (before hexp overwrites hbf)
// ---------------------------------------------------------------------------
__global__ __launch_bounds__(256) void hlast_kernel(
    const unsigned short* __restrict__ hbf, float* __restrict__ hlast)
{
    int i = blockIdx.x * 256 + threadIdx.x;
    if (i >= NB * HD) return;
    int n = i >> 9, c = i & 511;
    hlast[i] = b2f(hbf[((size_t)(n * LSEQ + (LSEQ - 1))) * HD + c]);
}

// ---------------------------------------------------------------------------
// LayerNorm: out1 = LN(hbf + inp) * gamma + beta  (2 elems/thread, ushort2)
// ---------------------------------------------------------------------------
__global__ __launch_bounds__(256) void ln_kernel(
    const unsigned short* __restrict__ hbf, const float* __restrict__ inp,
    const float* __restrict__ gamma, const float* __restrict__ beta,
    float* __restrict__ out1)
{
    size_t row = blockIdx.x;
    int tid = threadIdx.x;
    int c = tid * 2;
    const unsigned short* yrow = hbf + row * HD;
    const float* xrow = inp + row * HD;
    ushort2 yv = *(const ushort2*)(yrow + c);
    float2 xv = *(const float2*)(xrow + c);
    float a = b2f(yv.x) + xv.x;
    float b = b2f(yv.y) + xv.y;
    float s = a + b, ss = a * a + b * b;
    #pragma unroll
    for (int m = 1; m < 64; m <<= 1) {
        s  += __shfl_xor(s, m, 64);
        ss += __shfl_xor(ss, m, 64);
    }
    __shared__ float ps[4], pss[4];
    int w = tid >> 6;
    if ((tid & 63) == 0) { ps[w] = s; pss[w] = ss; }
    __syncthreads();
    s  = ps[0] + ps[1] + ps[2] + ps[3];
    ss = pss[0] + pss[1] + pss[2] + pss[3];
    float mu = s * (1.f / 512.f);
    float var = ss * (1.f / 512.f) - mu * mu;
    float inv = rsqrtf(var + 1e-5f);
    float2 gv = *(const float2*)(gamma + c);
    float2 bv = *(const float2*)(beta + c);
    float2 o;
    o.x = (a - mu) * inv * gv.x + bv.x;
    o.y = (b - mu) * inv * gv.y + bv.y;
    *(float2*)(out1 + row * HD + c) = o;
}

// ---------------------------------------------------------------------------
// hexp: out2[n,l,:] = hlast[n,:]  (overwrites hbf/gxn scratch; runs last)
// ---------------------------------------------------------------------------
__global__ __launch_bounds__(256) void hexp_kernel(
    const float* __restrict__ hlast, float* __restrict__ out2)
{
    size_t idx = (size_t)blockIdx.x * 256 + threadIdx.x;   // float4 units
    if (idx >= (size_t)NI * HD / 4) return;
    int per_n = LSEQ * HD / 4;
    int n = (int)(idx / per_n);
    int c4 = (int)(idx & (HD / 4 - 1));
    float4 v = *(const float4*)(hlast + n * HD + c4 * 4);
    *(float4*)(out2 + idx * 4) = v;
}

// ---------------------------------------------------------------------------
extern "C" void kernel_launch(void* const* d_in, const int* in_sizes, int n_in,
                              void* d_out, int out_size, void* d_ws, size_t ws_size,
                              hipStream_t stream)
{
    const float* inp   = (const float*)d_in[0];
    const float* h0    = (const float*)d_in[1];
    const int*  is_ini = (const int*)d_in[2];
    const float* W_ih  = (const float*)d_in[3];
    const float* W_hh  = (const float*)d_in[4];
    const float* b_ih  = (const float*)d_in[5];
    const float* b_hh  = (const float*)d_in[6];
    const float* gamma = (const float*)d_in[7];
    const float* beta  = (const float*)d_in[8];

    const size_t NLH = (size_t)NI * HD;            // 33,554,432
    float* out1 = (float*)d_out;
    float* out2 = out1 + NLH;
    // scratch overlay on d_out (268 MB total):
    //   out1: gx_r (67MB bf16) + gx_z (67MB)   -- overwritten by ln at the end
    //   out2: hbf  (67MB bf16) + gx_n (67MB)   -- overwritten by hexp at the end
    unsigned short* gxr = (unsigned short*)out1;
    unsigned short* gxz = gxr + NLH;
    unsigned short* hbf = (unsigned short*)out2;
    unsigned short* gxn = hbf + NLH;

    unsigned short* Xpack = (unsigned short*)d_ws;            // 1.5 MB
    unsigned short* Hpack = Xpack + 1536 * 512;               // 1.5 MB
    int* counts  = (int*)(Hpack + 1536 * 512);                // 2 KB
    int* offsets = counts + LSEQ;                             // 2 KB
    unsigned* items = (unsigned*)(offsets + LSEQ);            // 256 KB
    unsigned short* h0bf = (unsigned short*)(items + NI);     // 128 KB
    unsigned short* zeropage = h0bf + NB * HD;                // 2 KB
    float* hlast = (float*)(zeropage + 1024);                 // 256 KB

    setup_kernel<<<(NB * HD + 255) / 256, 256, 0, stream>>>(h0, h0bf, zeropage);
    pack_kernel<<<(1536 * 512 + 255) / 256, 256, 0, stream>>>(W_ih, W_hh, Xpack, Hpack);
    sched_kernel<<<1, 128, 0, stream>>>(is_ini, counts, offsets, items);

    gx_kernel<<<dim3(NI / 64, 3), 512, 0, stream>>>(inp, Xpack, b_ih, gxr, gxz, gxn);

    for (int d = 0; d < MAX_DEPTH; d++) {
        int gx = 512 >> d;
        if (gx < 2) gx = 2;
        phase_kernel<<<dim3(gx, 2), 512, 0, stream>>>(
            d, Hpack, b_hh, counts, offsets, items,
            gxr, gxz, gxn, h0bf, zeropage, is_ini, hbf);
    }

    hlast_kernel<<<(NB * HD + 255) / 256, 256, 0, stream>>>(hbf, hlast);
    ln_kernel<<<NI, 256, 0, stream>>>(hbf, inp, gamma, beta, out1);
    hexp_kernel<<<(int)(NLH / 4 / 256), 256, 0, stream>>>(hlast, out2);
}